// Round 20
// baseline (71.605 us; speedup 1.0000x reference)
//
#include <hip/hip_runtime.h>
#include <hip/hip_bf16.h>

// Pipeline: k_pre (fold weights) -> k_qk (MFMA 64x64, BK=64, reg-prefetch) ->
// k_attn (per-token, MFMA scores on 2 waves, merged LDS, wave-parallel softmax) ->
// k_out (64x16 tile, BK=128, reg-prefetch, grid 1024 = 2x occupancy).
//   scores[t,h,l] = s * T[t,l,:]·qk[t,h,:],  qk = S@Mt + bqk  (k-bias drop exact)
//   tbar[t,h,:]   = sum_l attn * T[t,l,:]
//   out           = tbar @ W2 + bo2          (v/o bias folds exact, sum attn = 1)
// MFMA garbage-row rule: D[r][c] depends only on A-row r and B-row c -> unread
// output rows/cols tolerate garbage operands (no zeroing needed).
// Occupancy law (5x confirmed): never trade blocks/CU for per-barrier amortization;
// k_out was grid-starved at 512 blocks (8 waves/CU) -> 1024 blocks (16 waves/CU).

#define L_ 24
#define C_ 256
#define H_ 8
#define D_ 32
#define NTOK 4096
#define SCALE 0.17677669529663687f   // 1/sqrt(32)

typedef __attribute__((ext_vector_type(8))) short short8;   // 8 bf16
typedef __attribute__((ext_vector_type(4))) float f32x4;

// workspace layout (bytes)
#define QK_OFF   ((size_t)0)                      // bf16 [4096][2048]
#define TBAR_OFF ((size_t)16777216)               // bf16 [4096][2048]
#define MT_OFF   ((size_t)33554432)               // bf16 [2048][256]  Mt[hc][e]
#define W2T_OFF  ((size_t)34603008)               // bf16 [256][2048]  W2t[e][hc]
#define BQK_OFF  ((size_t)35651584)               // f32 [2048]
#define BO2_OFF  ((size_t)35659776)               // f32 [256]
#define WS_NEED  ((size_t)35660800)

// ---------------- k_pre: weight folds (130 blocks x 256) ----------------
__global__ __launch_bounds__(256)
void k_pre(const float* __restrict__ Wq, const float* __restrict__ bq,
           const float* __restrict__ Wkv, const float* __restrict__ bkv,
           const float* __restrict__ Wo, const float* __restrict__ bo,
           char* __restrict__ ws)
{
    __hip_bfloat16* mt  = (__hip_bfloat16*)(ws + MT_OFF);
    __hip_bfloat16* w2t = (__hip_bfloat16*)(ws + W2T_OFF);
    float* bqk = (float*)(ws + BQK_OFF);
    float* bo2 = (float*)(ws + BO2_OFF);
    const int b = blockIdx.x, tid = threadIdx.x;
    __shared__ float sW[32][33];
    if (b < 128) {
        const bool isV = b >= 64;
        const int bb = isV ? b - 64 : b;
        const int h = bb >> 3, c0 = (bb & 7) * 32;
        {   // stage 32 rows (c0..c0+31) x 32 cols of Wk or Wv
            const int ci = tid >> 3, dq = (tid & 7) * 4;
            const float4 v = *(const float4*)(Wkv + (size_t)(c0 + ci) * 512 + (isV ? 256 : 0) + h * 32 + dq);
            sW[ci][dq + 0] = v.x; sW[ci][dq + 1] = v.y; sW[ci][dq + 2] = v.z; sW[ci][dq + 3] = v.w;
        }
        __syncthreads();
        const int e = tid;
        float wreg[32];
        if (!isV) {
            // Mt[h*256+c][e] = SCALE * sum_d Wq[e][h*32+d] * Wk[c][h*32+d]
#pragma unroll
            for (int dq = 0; dq < 32; dq += 4) {
                const float4 v = *(const float4*)(Wq + (size_t)e * 256 + h * 32 + dq);
                wreg[dq] = v.x; wreg[dq + 1] = v.y; wreg[dq + 2] = v.z; wreg[dq + 3] = v.w;
            }
            for (int ci = 0; ci < 32; ++ci) {
                float a = 0.f;
#pragma unroll
                for (int d = 0; d < 32; ++d) a = fmaf(wreg[d], sW[ci][d], a);
                mt[(size_t)(h * 256 + c0 + ci) * 256 + e] = __float2bfloat16(a * SCALE);
            }
        } else {
            // W2t[e][h*256+c] = sum_d Wv[c][h*32+d] * Wo[h*32+d][e]
#pragma unroll
            for (int d = 0; d < 32; ++d) wreg[d] = Wo[(size_t)(h * 32 + d) * 256 + e];
            __hip_bfloat16 accs[32];
            for (int ci = 0; ci < 32; ++ci) {
                float a = 0.f;
#pragma unroll
                for (int d = 0; d < 32; ++d) a = fmaf(wreg[d], sW[ci][d], a);
                accs[ci] = __float2bfloat16(a);
            }
#pragma unroll
            for (int g = 0; g < 4; ++g)
                *(uint4*)&w2t[(size_t)e * 2048 + h * 256 + c0 + g * 8] = *(const uint4*)&accs[g * 8];
        }
    } else if (b == 128) {
        // bqk[h*256+c] = SCALE * sum_d bq[h*32+d] * Wk[c][h*32+d]  (row-per-thread)
        const int c = tid;
        const float* row = Wkv + (size_t)c * 512;
#pragma unroll
        for (int h = 0; h < 8; ++h) {
            float a = 0.f;
#pragma unroll
            for (int dq = 0; dq < 32; dq += 4) {
                const float4 v = *(const float4*)(row + h * 32 + dq);
                a = fmaf(bq[h * 32 + dq + 0], v.x, a);
                a = fmaf(bq[h * 32 + dq + 1], v.y, a);
                a = fmaf(bq[h * 32 + dq + 2], v.z, a);
                a = fmaf(bq[h * 32 + dq + 3], v.w, a);
            }
            bqk[h * 256 + c] = a * SCALE;
        }
    } else {
        // bo2[e] = bo[e] + sum_hd bv[hd] * Wo[hd][e]
        const int e = tid;
        float a = bo[e];
        for (int hd = 0; hd < 256; ++hd)
            a = fmaf(bkv[256 + hd], Wo[(size_t)hd * 256 + e], a);
        bo2[e] = a;
    }
}

// -------- k_qk: qk = bf16(S)@Mt + bqk (64x64, BK=64, reg-prefetch pipeline) --------
__global__ __launch_bounds__(256)
void k_qk(const float* __restrict__ S, char* __restrict__ ws)
{
    const __hip_bfloat16* mt = (const __hip_bfloat16*)(ws + MT_OFF);
    const float* bqk = (const float*)(ws + BQK_OFF);
    __hip_bfloat16* qk = (__hip_bfloat16*)(ws + QK_OFF);
    __shared__ __hip_bfloat16 sA[64][72];   // stride 72 bf16 -> benign bank offset
    __shared__ __hip_bfloat16 sB[64][72];   // sB[n][k] (Mt rows are already [hc][e]=B^T)
    const int tid = threadIdx.x;
    const int bm = blockIdx.x & 63, bn = blockIdx.x >> 6;   // grid 64 x 32
    const int m0 = bm * 64, n0 = bn * 64;
    const int w = tid >> 6, L = tid & 63;
    const int wr = (w >> 1) * 32, wc = (w & 1) * 32;
    const int fr = L & 15, fk = (L >> 4) * 8;
    const int sr = tid >> 2, sc = (tid & 3) * 16;           // staging: 16 elems/thread
    const float* pa_base = S + (size_t)(m0 + sr) * 256 + sc;
    const __hip_bfloat16* pb_base = mt + (size_t)(n0 + sr) * 256 + sc;
    f32x4 acc[2][2] = {};
    // prologue: load k0=0 into regs
    float4 ra0 = *(const float4*)(pa_base + 0);
    float4 ra1 = *(const float4*)(pa_base + 4);
    float4 ra2 = *(const float4*)(pa_base + 8);
    float4 ra3 = *(const float4*)(pa_base + 12);
    uint4  rb0 = *(const uint4*)(pb_base + 0);
    uint4  rb1 = *(const uint4*)(pb_base + 8);
#pragma unroll
    for (int it = 0; it < 4; ++it) {
        {   // write current regs to LDS (fp32 -> bf16 pack for A)
            union { __hip_bfloat16 h[16]; uint4 u[2]; } pk;
            const float4 vv[4] = { ra0, ra1, ra2, ra3 };
#pragma unroll
            for (int q = 0; q < 4; ++q) {
                pk.h[q * 4 + 0] = __float2bfloat16(vv[q].x);
                pk.h[q * 4 + 1] = __float2bfloat16(vv[q].y);
                pk.h[q * 4 + 2] = __float2bfloat16(vv[q].z);
                pk.h[q * 4 + 3] = __float2bfloat16(vv[q].w);
            }
            *(uint4*)&sA[sr][sc]     = pk.u[0];
            *(uint4*)&sA[sr][sc + 8] = pk.u[1];
            *(uint4*)&sB[sr][sc]     = rb0;
            *(uint4*)&sB[sr][sc + 8] = rb1;
        }
        __syncthreads();
        if (it < 3) {   // issue next-iteration loads; latency hides under MFMA
            const int kn = (it + 1) * 64;
            ra0 = *(const float4*)(pa_base + kn + 0);
            ra1 = *(const float4*)(pa_base + kn + 4);
            ra2 = *(const float4*)(pa_base + kn + 8);
            ra3 = *(const float4*)(pa_base + kn + 12);
            rb0 = *(const uint4*)(pb_base + kn + 0);
            rb1 = *(const uint4*)(pb_base + kn + 8);
        }
#pragma unroll
        for (int kh = 0; kh < 2; ++kh) {
            const int fk2 = kh * 32 + fk;
            const short8 af0 = *(const short8*)&sA[wr +  0 + fr][fk2];
            const short8 af1 = *(const short8*)&sA[wr + 16 + fr][fk2];
            const short8 bf0 = *(const short8*)&sB[wc +  0 + fr][fk2];
            const short8 bf1 = *(const short8*)&sB[wc + 16 + fr][fk2];
            acc[0][0] = __builtin_amdgcn_mfma_f32_16x16x32_bf16(af0, bf0, acc[0][0], 0, 0, 0);
            acc[0][1] = __builtin_amdgcn_mfma_f32_16x16x32_bf16(af0, bf1, acc[0][1], 0, 0, 0);
            acc[1][0] = __builtin_amdgcn_mfma_f32_16x16x32_bf16(af1, bf0, acc[1][0], 0, 0, 0);
            acc[1][1] = __builtin_amdgcn_mfma_f32_16x16x32_bf16(af1, bf1, acc[1][1], 0, 0, 0);
        }
        __syncthreads();
    }
#pragma unroll
    for (int i = 0; i < 2; ++i)
#pragma unroll
    for (int j = 0; j < 2; ++j) {
        const int col = n0 + wc + j * 16 + fr;          // D: col = lane&15
        const float bb = bqk[col];
#pragma unroll
        for (int r = 0; r < 4; ++r) {
            const int row = m0 + wr + i * 16 + (L >> 4) * 4 + r;  // D: row = (lane>>4)*4+reg
            qk[(size_t)row * 2048 + col] = __float2bfloat16(acc[i][j][r] + bb);
        }
    }
}

// -- k_attn: one block/token; merged LDS buffer (qk rows 0-7, T rows 8-31),
//    MFMA scores split across 2 waves, wave-parallel softmax --
__global__ __launch_bounds__(256)
void k_attn(const float* __restrict__ T, char* __restrict__ ws)
{
    const __hip_bfloat16* qk = (const __hip_bfloat16*)(ws + QK_OFF);
    __hip_bfloat16* tbar = (__hip_bfloat16*)(ws + TBAR_OFF);
    // rows 0-7: qk[t] (A-operand); rows 8-31: T[t] bf16 (B-operand, base offset 8);
    // rows 32-39: uninit (read only by wave1's B frs 8-15 -> unread D cols 24-31;
    // A rows 8-15 read T rows 0-7 -> unread D rows 8-15).  22.2 KB total.
    __shared__ __hip_bfloat16   buf[40][264];
    __shared__ float            sAt[8][33];
    const int tid = threadIdx.x;
    const int t = blockIdx.x;
    {   // stage T[t] (24x256) -> bf16, rows 8..31
        const float4* Tv = (const float4*)(T + (size_t)t * 6144);
#pragma unroll
        for (int k = 0; k < 6; ++k) {
            const int f = tid + k * 256;
            const float4 v = Tv[f];
            const int l = f >> 6, c = (f & 63) * 4;
            __hip_bfloat16 b4[4] = { __float2bfloat16(v.x), __float2bfloat16(v.y),
                                     __float2bfloat16(v.z), __float2bfloat16(v.w) };
            *(uint2*)&buf[8 + l][c] = *(const uint2*)b4;
        }
    }
    {   // stage qk[t] bf16 -> rows 0..7 (cooperative, coalesced)
        const int h = tid >> 5, c = (tid & 31) * 8;
        *(uint4*)&buf[h][c] = *(const uint4*)(qk + (size_t)t * 2048 + tid * 8);
    }
    __syncthreads();
    {   // scores on 2 waves: wave0 -> l=0..15 (B rows 8+fr), wave1 -> l=16..23 (B rows 24+fr)
        const int wv = tid >> 6;
        if (wv < 2) {
            const int ln = tid & 63;
            const int fr = ln & 15, fk = (ln >> 4) * 8;
            const int bbase = (wv == 0) ? 8 : 24;
            f32x4 acc = {};
#pragma unroll
            for (int ks = 0; ks < 8; ++ks) {
                const short8 a = *(const short8*)&buf[fr][ks * 32 + fk];          // qk rows
                const short8 b = *(const short8*)&buf[bbase + fr][ks * 32 + fk];  // T slice
                acc = __builtin_amdgcn_mfma_f32_16x16x32_bf16(a, b, acc, 0, 0, 0);
            }
            if (ln < 32) {        // D: col(l)=lane&15, row(h)=(lane>>4)*4+reg
                const int hb = (ln >> 4) * 4, l0 = ln & 15;
                if (wv == 0) {
#pragma unroll
                    for (int r = 0; r < 4; ++r) sAt[hb + r][l0] = acc[r];
                } else if (l0 < 8) {
#pragma unroll
                    for (int r = 0; r < 4; ++r) sAt[hb + r][16 + l0] = acc[r];
                }
            }
        }
    }
    __syncthreads();
    if (tid < 64) {   // wave-parallel softmax: 8 lanes per head, 3 elems per lane
        const int g = tid >> 3, e = tid & 7;
        const int l0 = e * 3;
        const float s0 = sAt[g][l0], s1 = sAt[g][l0 + 1], s2 = sAt[g][l0 + 2];
        float m = fmaxf(fmaxf(s0, s1), s2);
        m = fmaxf(m, __shfl_xor(m, 1));
        m = fmaxf(m, __shfl_xor(m, 2));
        m = fmaxf(m, __shfl_xor(m, 4));
        const float e0 = __expf(s0 - m), e1 = __expf(s1 - m), e2 = __expf(s2 - m);
        float sum = e0 + e1 + e2;
        sum += __shfl_xor(sum, 1);
        sum += __shfl_xor(sum, 2);
        sum += __shfl_xor(sum, 4);
        const float inv = 1.0f / sum;
        sAt[g][l0]     = e0 * inv;
        sAt[g][l0 + 1] = e1 * inv;
        sAt[g][l0 + 2] = e2 * inv;
    }
    __syncthreads();
    {   // tbar[h][c0..c0+7] = sum_l attn * T  (bf16 T rows 8.., unpack in-flight)
        const int h = tid >> 5, c0 = (tid & 31) * 8;
        float acc[8] = {};
        for (int l = 0; l < 24; ++l) {
            const float a = sAt[h][l];
            const uint4 v = *(const uint4*)&buf[8 + l][c0];
            const unsigned int* pu = (const unsigned int*)&v;
#pragma unroll
            for (int j = 0; j < 4; ++j) {
                acc[2 * j]     = fmaf(a, __uint_as_float(pu[j] << 16),          acc[2 * j]);
                acc[2 * j + 1] = fmaf(a, __uint_as_float(pu[j] & 0xffff0000u), acc[2 * j + 1]);
            }
        }
        union { __hip_bfloat16 h8[8]; uint4 u; } pk;
#pragma unroll
        for (int j = 0; j < 8; ++j) pk.h8[j] = __float2bfloat16(acc[j]);
        *(uint4*)&tbar[(size_t)t * 2048 + tid * 8] = pk.u;
    }
}

// ---- k_out: Out = tbar @ W2 + bo2 (64x16 tile, BK=128, reg-prefetch, grid 1024) ----
__global__ __launch_bounds__(256)
void k_out(const char* __restrict__ ws, float* __restrict__ Out)
{
    const __hip_bfloat16* tbar = (const __hip_bfloat16*)(ws + TBAR_OFF);
    const __hip_bfloat16* w2t  = (const __hip_bfloat16*)(ws + W2T_OFF);
    const float* bo2 = (const float*)(ws + BO2_OFF);
    __shared__ __hip_bfloat16 sA[64][136];   // BK=128, stride 136 -> benign bank offset
    __shared__ __hip_bfloat16 sB[16][136];   // 16 N-rows
    const int tid = threadIdx.x;
    const int bm = blockIdx.x & 63, bn = blockIdx.x >> 6;   // grid 64 x 16
    const int m0 = bm * 64, n0 = bn * 16;
    const int w = tid >> 6, L = tid & 63;
    const int fr = L & 15, fkb = (L >> 4) * 8;
    const int ar = tid >> 2, ac = (tid & 3) * 32;           // A: 32 elems/thread
    const int br = tid >> 4, bc = (tid & 15) * 8;           // B: 8 elems/thread (16x128)
    const __hip_bfloat16* pa_base = tbar + (size_t)(m0 + ar) * 2048 + ac;
    const __hip_bfloat16* pb_base = w2t + (size_t)(n0 + br) * 2048 + bc;
    f32x4 acc = {};
    // prologue: load k0=0
    uint4 ra0 = *(const uint4*)(pa_base + 0);
    uint4 ra1 = *(const uint4*)(pa_base + 8);
    uint4 ra2 = *(const uint4*)(pa_base + 16);
    uint4 ra3 = *(const uint4*)(pa_base + 24);
    uint4 rb0 = *(const uint4*)(pb_base + 0);
    for (int it = 0; it < 16; ++it) {
        {
            *(uint4*)&sA[ar][ac]      = ra0;
            *(uint4*)&sA[ar][ac + 8]  = ra1;
            *(uint4*)&sA[ar][ac + 16] = ra2;
            *(uint4*)&sA[ar][ac + 24] = ra3;
            *(uint4*)&sB[br][bc]      = rb0;
        }
        __syncthreads();
        if (it < 15) {   // issue next-iteration loads; latency hides under MFMA
            const int kn = (it + 1) * 128;
            ra0 = *(const uint4*)(pa_base + kn + 0);
            ra1 = *(const uint4*)(pa_base + kn + 8);
            ra2 = *(const uint4*)(pa_base + kn + 16);
            ra3 = *(const uint4*)(pa_base + kn + 24);
            rb0 = *(const uint4*)(pb_base + kn + 0);
        }
#pragma unroll
        for (int sub = 0; sub < 4; ++sub) {
            const int kb = sub * 32 + fkb;
            const short8 af = *(const short8*)&sA[w * 16 + fr][kb];
            const short8 bf = *(const short8*)&sB[fr][kb];
            acc = __builtin_amdgcn_mfma_f32_16x16x32_bf16(af, bf, acc, 0, 0, 0);
        }
        __syncthreads();
    }
    {
        const int col = n0 + fr;
        const float bb = bo2[col];
#pragma unroll
        for (int r = 0; r < 4; ++r) {
            const int row = m0 + w * 16 + (L >> 4) * 4 + r;
            Out[(size_t)row * 256 + col] = acc[r] + bb;
        }
    }
}

// ================= fallback: round-3 proven fused kernel =================
#define NT    16
#define NTHR  512
#define NBLK  256
#define TSTR  (C_ + 4)
#define QKSTR (C_ + 8)
#define QSTR  (D_ + 4)
#define WKROW 268

__global__ __launch_bounds__(NTHR)
void t2s_attn_fused(const float* __restrict__ S, const float* __restrict__ T,
                    const float* __restrict__ Wq, const float* __restrict__ bq,
                    const float* __restrict__ Wkv, const float* __restrict__ bkv,
                    const float* __restrict__ Wo, const float* __restrict__ bo,
                    float* __restrict__ Out)
{
    __shared__ float            sQ[NT][H_][QSTR];
    __shared__ float            sWk[16 * WKROW];
    __shared__ float            sT[2][L_][TSTR];
    __shared__ __hip_bfloat16   sQKT[NT][H_][QKSTR];
    __shared__ float            sSc[H_][L_ + 8];
    const int tid = threadIdx.x;
    const int g0  = blockIdx.x * NT;
    float4 tp0, tp1, tp2;
    {
        const float* tb = T + (size_t)g0 * (L_ * C_);
        tp0 = *(const float4*)(tb + 0 * 2048 + tid * 4);
        tp1 = *(const float4*)(tb + 1 * 2048 + tid * 4);
        tp2 = *(const float4*)(tb + 2 * 2048 + tid * 4);
    }
    {
        const int col = tid & 255;
        const int t0  = (tid >> 8) * 8;
        float acc[8];
        const float bqv = bq[col];
#pragma unroll
        for (int j = 0; j < 8; ++j) acc[j] = bqv;
        const float* sp = S + (size_t)(g0 + t0) * C_;
        for (int c = 0; c < C_; ++c) {
            const float w = Wq[c * C_ + col];
#pragma unroll
            for (int j = 0; j < 8; ++j)
                acc[j] = fmaf(sp[j * C_ + c], w, acc[j]);
        }
#pragma unroll
        for (int j = 0; j < 8; ++j)
            sQ[t0 + j][col >> 5][col & 31] = acc[j];
    }
    {
        const int e = tid * 4;
        *(float4*)&sT[0][(e >> 8) +  0][e & 255] = tp0;
        *(float4*)&sT[0][(e >> 8) +  8][e & 255] = tp1;
        *(float4*)&sT[0][(e >> 8) + 16][e & 255] = tp2;
    }
    __syncthreads();
    {
        const int cq = tid & 3;
        const int h  = (tid >> 2) & 7;
        const int t  = tid >> 5;
        for (int ct = 0; ct < 16; ++ct) {
            {
                const int hd  = tid & 255, ci2 = tid >> 8;
                const float* wsrc = Wkv + (size_t)(ct * 16) * 512;
#pragma unroll
                for (int j = 0; j < 8; ++j) {
                    const int ci = ci2 + j * 2;
                    sWk[ci * WKROW + (hd >> 5) * 33 + (hd & 31)] = wsrc[(size_t)ci * 512 + hd];
                }
            }
            __syncthreads();
            float a0 = 0.f, a1 = 0.f, a2 = 0.f, a3 = 0.f;
            const float* qrow = &sQ[t][h][0];
            const float* wb   = &sWk[(cq * 4) * WKROW + h * 33];
#pragma unroll
            for (int d = 0; d < D_; ++d) {
                const float qv = qrow[d];
                a0 = fmaf(qv, wb[0 * WKROW + d], a0);
                a1 = fmaf(qv, wb[1 * WKROW + d], a1);
                a2 = fmaf(qv, wb[2 * WKROW + d], a2);
                a3 = fmaf(qv, wb[3 * WKROW + d], a3);
            }
            const int c0 = ct * 16 + cq * 4;
            sQKT[t][h][c0 + 0] = __float2bfloat16(a0);
            sQKT[t][h][c0 + 1] = __float2bfloat16(a1);
            sQKT[t][h][c0 + 2] = __float2bfloat16(a2);
            sQKT[t][h][c0 + 3] = __float2bfloat16(a3);
            __syncthreads();
        }
    }
    const int lane = tid & 63, wav = tid >> 6;
    for (int t = 0; t < NT; ++t) {
        const int cur = t & 1;
        const bool pf = (t + 1 < NT);
        if (pf) {
            const float* tb = T + (size_t)(g0 + t + 1) * (L_ * C_);
            tp0 = *(const float4*)(tb + 0 * 2048 + tid * 4);
            tp1 = *(const float4*)(tb + 1 * 2048 + tid * 4);
            tp2 = *(const float4*)(tb + 2 * 2048 + tid * 4);
        }
        if (tid < 192) {
            const int h = tid / 24, l = tid - h * 24;
            const float* trow = &sT[cur][l][0];
            const unsigned short* qkr = (const unsigned short*)&sQKT[t][h][0];
            float a0 = 0.f, a1 = 0.f, a2 = 0.f, a3 = 0.f;
            for (int c = 0; c < C_; c += 4) {
                const float4 tv = *(const float4*)(trow + c);
                const uint2  qu = *(const uint2*)(qkr + c);
                a0 = fmaf(tv.x, __uint_as_float(qu.x << 16),          a0);
                a1 = fmaf(tv.y, __uint_as_float(qu.x & 0xffff0000u), a1);
                a2 = fmaf(tv.z, __uint_as_float(qu.y << 16),          a2);
                a3 = fmaf(tv.w, __uint_as_float(qu.y & 0xffff0000u), a3);
            }
            sSc[h][l] = (a0 + a1 + a2 + a3) * 0.17677669529663687f;
        }
        __syncthreads();
        if (tid < 8) {
            float mx = -1e30f;
#pragma unroll
            for (int l = 0; l < L_; ++l) mx = fmaxf(mx, sSc[tid][l]);
            float e[L_]; float sum = 0.f;
#pragma unroll
            for (int l = 0; l < L_; ++l) { e[l] = __expf(sSc[tid][l] - mx); sum += e[l]; }
            const float inv = 1.0f / sum;
#pragma unroll
            for (int l = 0; l < L_; ++l) sSc[tid][l] = e[l] * inv;
        }
        __syncthreads();
        {
            const int h = wav, c0 = lane * 4;
            float ax = 0.f, ay = 0.f, az = 0.f, aw = 0.f;
            const float* at = &sSc[h][0];
#pragma unroll
            for (int l = 0; l < L_; ++l) {
                const float  a  = at[l];
                const float4 tv = *(const float4*)&sT[cur][l][c0];
                ax = fmaf(a, tv.x, ax); ay = fmaf(a, tv.y, ay);
                az = fmaf(a, tv.z, az); aw = fmaf(a, tv.w, aw);
            }
            sQKT[t][h][c0 + 0] = __float2bfloat16(ax);
            sQKT[t][h][c0 + 1] = __float2bfloat16(ay);
            sQKT[t][h][c0 + 2] = __float2bfloat16(az);
            sQKT[t][h][c0 + 3] = __float2bfloat16(aw);
        }
        if (pf) {
            const int e = tid * 4;
            *(float4*)&sT[cur ^ 1][(e >> 8) +  0][e & 255] = tp0;
            *(float4*)&sT[cur ^ 1][(e >> 8) +  8][e & 255] = tp1;
            *(float4*)&sT[cur ^ 1][(e >> 8) + 16][e & 255] = tp2;
        }
        __syncthreads();
    }
    {
        const int hd = tid & 255;
        const int h  = hd >> 5;
        const int t0 = (tid >> 8) * 8;
        float acc[8];
        const float bv = bkv[C_ + hd];
#pragma unroll
        for (int j = 0; j < 8; ++j) acc[j] = bv;
        const float* wv = Wkv + C_ + hd;
        for (int c = 0; c < C_; c += 2) {
            const float w0 = wv[(size_t)c * 512];
            const float w1 = wv[(size_t)(c + 1) * 512];
#pragma unroll
            for (int j = 0; j < 8; ++j) {
                const unsigned int u = *(const unsigned int*)&sQKT[t0 + j][h][c];
                acc[j] = fmaf(__uint_as_float(u << 16),          w0, acc[j]);
                acc[j] = fmaf(__uint_as_float(u & 0xffff0000u), w1, acc[j]);
            }
        }
#pragma unroll
        for (int j = 0; j < 8; ++j)
            sQ[t0 + j][h][hd & 31] = acc[j];
    }
    __syncthreads();
    {
        const int col = tid & 255;
        const int t0  = (tid >> 8) * 8;
        float acc[8];
        const float bov = bo[col];
#pragma unroll
        for (int j = 0; j < 8; ++j) acc[j] = bov;
        for (int hd = 0; hd < C_; ++hd) {
            const float w  = Wo[hd * C_ + col];
            const int  hh = hd >> 5, dd = hd & 31;
#pragma unroll
            for (int j = 0; j < 8; ++j)
                acc[j] = fmaf(sQ[t0 + j][hh][dd], w, acc[j]);
        }
#pragma unroll
        for (int j = 0; j < 8; ++j)
            Out[(size_t)(g0 + t0 + j) * C_ + col] = acc[j];
    }
}

extern "C" void kernel_launch(void* const* d_in, const int* in_sizes, int n_in,
                              void* d_out, int out_size, void* d_ws, size_t ws_size,
                              hipStream_t stream) {
    const float* S   = (const float*)d_in[0];
    const float* T   = (const float*)d_in[1];
    const float* Wq  = (const float*)d_in[2];
    const float* bq  = (const float*)d_in[3];
    const float* Wkv = (const float*)d_in[4];
    const float* bkv = (const float*)d_in[5];
    const float* Wo  = (const float*)d_in[6];
    const float* bo  = (const float*)d_in[7];
    float* Out = (float*)d_out;
    if (ws_size >= WS_NEED) {
        char* ws = (char*)d_ws;
        hipLaunchKernelGGL(k_pre,  dim3(130),  dim3(256), 0, stream, Wq, bq, Wkv, bkv, Wo, bo, ws);
        hipLaunchKernelGGL(k_qk,   dim3(2048), dim3(256), 0, stream, S, ws);
        hipLaunchKernelGGL(k_attn, dim3(4096), dim3(256), 0, stream, T, ws);
        hipLaunchKernelGGL(k_out,  dim3(1024), dim3(256), 0, stream, ws, Out);
    } else {
        hipLaunchKernelGGL(t2s_attn_fused, dim3(NBLK), dim3(NTHR), 0, stream,
                           S, T, Wq, bq, Wkv, bkv, Wo, bo, Out);
    }
}

// Round 21
// 66.872 us; speedup vs baseline: 1.0708x; 1.0708x over previous
//
#include <hip/hip_runtime.h>
#include <hip/hip_bf16.h>

// Pipeline: k_pre (fold weights) -> k_qk (MFMA 64x64, BK=64, reg-prefetch) ->
// k_attn (per-token, MFMA scores on 2 waves, merged LDS, wave-parallel softmax) ->
// k_out (64x32 tile, BK=128, reg-prefetch, grid 512).  Exact algebra:
//   scores[t,h,l] = s * T[t,l,:]·qk[t,h,:],  qk = S@Mt + bqk  (k-bias drop exact)
//   tbar[t,h,:]   = sum_l attn * T[t,l,:]
//   out           = tbar @ W2 + bo2          (v/o bias folds exact, sum attn = 1)
// MFMA garbage-row rule: D[r][c] depends only on A-row r and B-row c -> unread
// output rows/cols tolerate garbage operands (no zeroing needed).
// Occupancy law (bounded, r20): more blocks/CU wins ONLY if it doesn't multiply
// operand re-reads or drop in-loop MFMA ILP (k_out 64x16/grid1024 regressed +4.4us).
// This is the best-known configuration (r18, 67.2us).

#define L_ 24
#define C_ 256
#define H_ 8
#define D_ 32
#define NTOK 4096
#define SCALE 0.17677669529663687f   // 1/sqrt(32)

typedef __attribute__((ext_vector_type(8))) short short8;   // 8 bf16
typedef __attribute__((ext_vector_type(4))) float f32x4;

// workspace layout (bytes)
#define QK_OFF   ((size_t)0)                      // bf16 [4096][2048]
#define TBAR_OFF ((size_t)16777216)               // bf16 [4096][2048]
#define MT_OFF   ((size_t)33554432)               // bf16 [2048][256]  Mt[hc][e]
#define W2T_OFF  ((size_t)34603008)               // bf16 [256][2048]  W2t[e][hc]
#define BQK_OFF  ((size_t)35651584)               // f32 [2048]
#define BO2_OFF  ((size_t)35659776)               // f32 [256]
#define WS_NEED  ((size_t)35660800)

// ---------------- k_pre: weight folds (130 blocks x 256) ----------------
__global__ __launch_bounds__(256)
void k_pre(const float* __restrict__ Wq, const float* __restrict__ bq,
           const float* __restrict__ Wkv, const float* __restrict__ bkv,
           const float* __restrict__ Wo, const float* __restrict__ bo,
           char* __restrict__ ws)
{
    __hip_bfloat16* mt  = (__hip_bfloat16*)(ws + MT_OFF);
    __hip_bfloat16* w2t = (__hip_bfloat16*)(ws + W2T_OFF);
    float* bqk = (float*)(ws + BQK_OFF);
    float* bo2 = (float*)(ws + BO2_OFF);
    const int b = blockIdx.x, tid = threadIdx.x;
    __shared__ float sW[32][33];
    if (b < 128) {
        const bool isV = b >= 64;
        const int bb = isV ? b - 64 : b;
        const int h = bb >> 3, c0 = (bb & 7) * 32;
        {   // stage 32 rows (c0..c0+31) x 32 cols of Wk or Wv
            const int ci = tid >> 3, dq = (tid & 7) * 4;
            const float4 v = *(const float4*)(Wkv + (size_t)(c0 + ci) * 512 + (isV ? 256 : 0) + h * 32 + dq);
            sW[ci][dq + 0] = v.x; sW[ci][dq + 1] = v.y; sW[ci][dq + 2] = v.z; sW[ci][dq + 3] = v.w;
        }
        __syncthreads();
        const int e = tid;
        float wreg[32];
        if (!isV) {
            // Mt[h*256+c][e] = SCALE * sum_d Wq[e][h*32+d] * Wk[c][h*32+d]
#pragma unroll
            for (int dq = 0; dq < 32; dq += 4) {
                const float4 v = *(const float4*)(Wq + (size_t)e * 256 + h * 32 + dq);
                wreg[dq] = v.x; wreg[dq + 1] = v.y; wreg[dq + 2] = v.z; wreg[dq + 3] = v.w;
            }
            for (int ci = 0; ci < 32; ++ci) {
                float a = 0.f;
#pragma unroll
                for (int d = 0; d < 32; ++d) a = fmaf(wreg[d], sW[ci][d], a);
                mt[(size_t)(h * 256 + c0 + ci) * 256 + e] = __float2bfloat16(a * SCALE);
            }
        } else {
            // W2t[e][h*256+c] = sum_d Wv[c][h*32+d] * Wo[h*32+d][e]
#pragma unroll
            for (int d = 0; d < 32; ++d) wreg[d] = Wo[(size_t)(h * 32 + d) * 256 + e];
            __hip_bfloat16 accs[32];
            for (int ci = 0; ci < 32; ++ci) {
                float a = 0.f;
#pragma unroll
                for (int d = 0; d < 32; ++d) a = fmaf(wreg[d], sW[ci][d], a);
                accs[ci] = __float2bfloat16(a);
            }
#pragma unroll
            for (int g = 0; g < 4; ++g)
                *(uint4*)&w2t[(size_t)e * 2048 + h * 256 + c0 + g * 8] = *(const uint4*)&accs[g * 8];
        }
    } else if (b == 128) {
        // bqk[h*256+c] = SCALE * sum_d bq[h*32+d] * Wk[c][h*32+d]  (row-per-thread)
        const int c = tid;
        const float* row = Wkv + (size_t)c * 512;
#pragma unroll
        for (int h = 0; h < 8; ++h) {
            float a = 0.f;
#pragma unroll
            for (int dq = 0; dq < 32; dq += 4) {
                const float4 v = *(const float4*)(row + h * 32 + dq);
                a = fmaf(bq[h * 32 + dq + 0], v.x, a);
                a = fmaf(bq[h * 32 + dq + 1], v.y, a);
                a = fmaf(bq[h * 32 + dq + 2], v.z, a);
                a = fmaf(bq[h * 32 + dq + 3], v.w, a);
            }
            bqk[h * 256 + c] = a * SCALE;
        }
    } else {
        // bo2[e] = bo[e] + sum_hd bv[hd] * Wo[hd][e]
        const int e = tid;
        float a = bo[e];
        for (int hd = 0; hd < 256; ++hd)
            a = fmaf(bkv[256 + hd], Wo[(size_t)hd * 256 + e], a);
        bo2[e] = a;
    }
}

// -------- k_qk: qk = bf16(S)@Mt + bqk (64x64, BK=64, reg-prefetch pipeline) --------
__global__ __launch_bounds__(256)
void k_qk(const float* __restrict__ S, char* __restrict__ ws)
{
    const __hip_bfloat16* mt = (const __hip_bfloat16*)(ws + MT_OFF);
    const float* bqk = (const float*)(ws + BQK_OFF);
    __hip_bfloat16* qk = (__hip_bfloat16*)(ws + QK_OFF);
    __shared__ __hip_bfloat16 sA[64][72];   // stride 72 bf16 -> benign bank offset
    __shared__ __hip_bfloat16 sB[64][72];   // sB[n][k] (Mt rows are already [hc][e]=B^T)
    const int tid = threadIdx.x;
    const int bm = blockIdx.x & 63, bn = blockIdx.x >> 6;   // grid 64 x 32
    const int m0 = bm * 64, n0 = bn * 64;
    const int w = tid >> 6, L = tid & 63;
    const int wr = (w >> 1) * 32, wc = (w & 1) * 32;
    const int fr = L & 15, fk = (L >> 4) * 8;
    const int sr = tid >> 2, sc = (tid & 3) * 16;           // staging: 16 elems/thread
    const float* pa_base = S + (size_t)(m0 + sr) * 256 + sc;
    const __hip_bfloat16* pb_base = mt + (size_t)(n0 + sr) * 256 + sc;
    f32x4 acc[2][2] = {};
    // prologue: load k0=0 into regs
    float4 ra0 = *(const float4*)(pa_base + 0);
    float4 ra1 = *(const float4*)(pa_base + 4);
    float4 ra2 = *(const float4*)(pa_base + 8);
    float4 ra3 = *(const float4*)(pa_base + 12);
    uint4  rb0 = *(const uint4*)(pb_base + 0);
    uint4  rb1 = *(const uint4*)(pb_base + 8);
#pragma unroll
    for (int it = 0; it < 4; ++it) {
        {   // write current regs to LDS (fp32 -> bf16 pack for A)
            union { __hip_bfloat16 h[16]; uint4 u[2]; } pk;
            const float4 vv[4] = { ra0, ra1, ra2, ra3 };
#pragma unroll
            for (int q = 0; q < 4; ++q) {
                pk.h[q * 4 + 0] = __float2bfloat16(vv[q].x);
                pk.h[q * 4 + 1] = __float2bfloat16(vv[q].y);
                pk.h[q * 4 + 2] = __float2bfloat16(vv[q].z);
                pk.h[q * 4 + 3] = __float2bfloat16(vv[q].w);
            }
            *(uint4*)&sA[sr][sc]     = pk.u[0];
            *(uint4*)&sA[sr][sc + 8] = pk.u[1];
            *(uint4*)&sB[sr][sc]     = rb0;
            *(uint4*)&sB[sr][sc + 8] = rb1;
        }
        __syncthreads();
        if (it < 3) {   // issue next-iteration loads; latency hides under MFMA
            const int kn = (it + 1) * 64;
            ra0 = *(const float4*)(pa_base + kn + 0);
            ra1 = *(const float4*)(pa_base + kn + 4);
            ra2 = *(const float4*)(pa_base + kn + 8);
            ra3 = *(const float4*)(pa_base + kn + 12);
            rb0 = *(const uint4*)(pb_base + kn + 0);
            rb1 = *(const uint4*)(pb_base + kn + 8);
        }
#pragma unroll
        for (int kh = 0; kh < 2; ++kh) {
            const int fk2 = kh * 32 + fk;
            const short8 af0 = *(const short8*)&sA[wr +  0 + fr][fk2];
            const short8 af1 = *(const short8*)&sA[wr + 16 + fr][fk2];
            const short8 bf0 = *(const short8*)&sB[wc +  0 + fr][fk2];
            const short8 bf1 = *(const short8*)&sB[wc + 16 + fr][fk2];
            acc[0][0] = __builtin_amdgcn_mfma_f32_16x16x32_bf16(af0, bf0, acc[0][0], 0, 0, 0);
            acc[0][1] = __builtin_amdgcn_mfma_f32_16x16x32_bf16(af0, bf1, acc[0][1], 0, 0, 0);
            acc[1][0] = __builtin_amdgcn_mfma_f32_16x16x32_bf16(af1, bf0, acc[1][0], 0, 0, 0);
            acc[1][1] = __builtin_amdgcn_mfma_f32_16x16x32_bf16(af1, bf1, acc[1][1], 0, 0, 0);
        }
        __syncthreads();
    }
#pragma unroll
    for (int i = 0; i < 2; ++i)
#pragma unroll
    for (int j = 0; j < 2; ++j) {
        const int col = n0 + wc + j * 16 + fr;          // D: col = lane&15
        const float bb = bqk[col];
#pragma unroll
        for (int r = 0; r < 4; ++r) {
            const int row = m0 + wr + i * 16 + (L >> 4) * 4 + r;  // D: row = (lane>>4)*4+reg
            qk[(size_t)row * 2048 + col] = __float2bfloat16(acc[i][j][r] + bb);
        }
    }
}

// -- k_attn: one block/token; merged LDS buffer (qk rows 0-7, T rows 8-31),
//    MFMA scores split across 2 waves, wave-parallel softmax --
__global__ __launch_bounds__(256)
void k_attn(const float* __restrict__ T, char* __restrict__ ws)
{
    const __hip_bfloat16* qk = (const __hip_bfloat16*)(ws + QK_OFF);
    __hip_bfloat16* tbar = (__hip_bfloat16*)(ws + TBAR_OFF);
    // rows 0-7: qk[t] (A-operand); rows 8-31: T[t] bf16 (B-operand, base offset 8);
    // rows 32-39: uninit (read only by wave1's B frs 8-15 -> unread D cols 24-31;
    // A rows 8-15 read T rows 0-7 -> unread D rows 8-15).  22.2 KB total.
    __shared__ __hip_bfloat16   buf[40][264];
    __shared__ float            sAt[8][33];
    const int tid = threadIdx.x;
    const int t = blockIdx.x;
    {   // stage T[t] (24x256) -> bf16, rows 8..31
        const float4* Tv = (const float4*)(T + (size_t)t * 6144);
#pragma unroll
        for (int k = 0; k < 6; ++k) {
            const int f = tid + k * 256;
            const float4 v = Tv[f];
            const int l = f >> 6, c = (f & 63) * 4;
            __hip_bfloat16 b4[4] = { __float2bfloat16(v.x), __float2bfloat16(v.y),
                                     __float2bfloat16(v.z), __float2bfloat16(v.w) };
            *(uint2*)&buf[8 + l][c] = *(const uint2*)b4;
        }
    }
    {   // stage qk[t] bf16 -> rows 0..7 (cooperative, coalesced)
        const int h = tid >> 5, c = (tid & 31) * 8;
        *(uint4*)&buf[h][c] = *(const uint4*)(qk + (size_t)t * 2048 + tid * 8);
    }
    __syncthreads();
    {   // scores on 2 waves: wave0 -> l=0..15 (B rows 8+fr), wave1 -> l=16..23 (B rows 24+fr)
        const int wv = tid >> 6;
        if (wv < 2) {
            const int ln = tid & 63;
            const int fr = ln & 15, fk = (ln >> 4) * 8;
            const int bbase = (wv == 0) ? 8 : 24;
            f32x4 acc = {};
#pragma unroll
            for (int ks = 0; ks < 8; ++ks) {
                const short8 a = *(const short8*)&buf[fr][ks * 32 + fk];          // qk rows
                const short8 b = *(const short8*)&buf[bbase + fr][ks * 32 + fk];  // T slice
                acc = __builtin_amdgcn_mfma_f32_16x16x32_bf16(a, b, acc, 0, 0, 0);
            }
            if (ln < 32) {        // D: col(l)=lane&15, row(h)=(lane>>4)*4+reg
                const int hb = (ln >> 4) * 4, l0 = ln & 15;
                if (wv == 0) {
#pragma unroll
                    for (int r = 0; r < 4; ++r) sAt[hb + r][l0] = acc[r];
                } else if (l0 < 8) {
#pragma unroll
                    for (int r = 0; r < 4; ++r) sAt[hb + r][16 + l0] = acc[r];
                }
            }
        }
    }
    __syncthreads();
    if (tid < 64) {   // wave-parallel softmax: 8 lanes per head, 3 elems per lane
        const int g = tid >> 3, e = tid & 7;
        const int l0 = e * 3;
        const float s0 = sAt[g][l0], s1 = sAt[g][l0 + 1], s2 = sAt[g][l0 + 2];
        float m = fmaxf(fmaxf(s0, s1), s2);
        m = fmaxf(m, __shfl_xor(m, 1));
        m = fmaxf(m, __shfl_xor(m, 2));
        m = fmaxf(m, __shfl_xor(m, 4));
        const float e0 = __expf(s0 - m), e1 = __expf(s1 - m), e2 = __expf(s2 - m);
        float sum = e0 + e1 + e2;
        sum += __shfl_xor(sum, 1);
        sum += __shfl_xor(sum, 2);
        sum += __shfl_xor(sum, 4);
        const float inv = 1.0f / sum;
        sAt[g][l0]     = e0 * inv;
        sAt[g][l0 + 1] = e1 * inv;
        sAt[g][l0 + 2] = e2 * inv;
    }
    __syncthreads();
    {   // tbar[h][c0..c0+7] = sum_l attn * T  (bf16 T rows 8.., unpack in-flight)
        const int h = tid >> 5, c0 = (tid & 31) * 8;
        float acc[8] = {};
        for (int l = 0; l < 24; ++l) {
            const float a = sAt[h][l];
            const uint4 v = *(const uint4*)&buf[8 + l][c0];
            const unsigned int* pu = (const unsigned int*)&v;
#pragma unroll
            for (int j = 0; j < 4; ++j) {
                acc[2 * j]     = fmaf(a, __uint_as_float(pu[j] << 16),          acc[2 * j]);
                acc[2 * j + 1] = fmaf(a, __uint_as_float(pu[j] & 0xffff0000u), acc[2 * j + 1]);
            }
        }
        union { __hip_bfloat16 h8[8]; uint4 u; } pk;
#pragma unroll
        for (int j = 0; j < 8; ++j) pk.h8[j] = __float2bfloat16(acc[j]);
        *(uint4*)&tbar[(size_t)t * 2048 + tid * 8] = pk.u;
    }
}

// ---- k_out: Out = tbar @ W2 + bo2 (64x32, BK=128, reg-prefetch, grid 512) ----
__global__ __launch_bounds__(256)
void k_out(const char* __restrict__ ws, float* __restrict__ Out)
{
    const __hip_bfloat16* tbar = (const __hip_bfloat16*)(ws + TBAR_OFF);
    const __hip_bfloat16* w2t  = (const __hip_bfloat16*)(ws + W2T_OFF);
    const float* bo2 = (const float*)(ws + BO2_OFF);
    __shared__ __hip_bfloat16 sA[64][136];   // BK=128, stride 136 -> benign bank offset
    __shared__ __hip_bfloat16 sB[32][136];
    const int tid = threadIdx.x;
    const int bm = blockIdx.x & 63, bn = blockIdx.x >> 6;   // grid 64 x 8
    const int m0 = bm * 64, n0 = bn * 32;
    const int w = tid >> 6, L = tid & 63;
    const int fr = L & 15, fkb = (L >> 4) * 8;
    const int ar = tid >> 2, ac = (tid & 3) * 32;           // A: 32 elems/thread
    const int br = tid >> 3, bc = (tid & 7) * 16;           // B: 16 elems/thread
    const __hip_bfloat16* pa_base = tbar + (size_t)(m0 + ar) * 2048 + ac;
    const __hip_bfloat16* pb_base = w2t + (size_t)(n0 + br) * 2048 + bc;
    f32x4 acc[2] = {};
    // prologue: load k0=0
    uint4 ra0 = *(const uint4*)(pa_base + 0);
    uint4 ra1 = *(const uint4*)(pa_base + 8);
    uint4 ra2 = *(const uint4*)(pa_base + 16);
    uint4 ra3 = *(const uint4*)(pa_base + 24);
    uint4 rb0 = *(const uint4*)(pb_base + 0);
    uint4 rb1 = *(const uint4*)(pb_base + 8);
    for (int it = 0; it < 16; ++it) {
        {
            *(uint4*)&sA[ar][ac]      = ra0;
            *(uint4*)&sA[ar][ac + 8]  = ra1;
            *(uint4*)&sA[ar][ac + 16] = ra2;
            *(uint4*)&sA[ar][ac + 24] = ra3;
            *(uint4*)&sB[br][bc]     = rb0;
            *(uint4*)&sB[br][bc + 8] = rb1;
        }
        __syncthreads();
        if (it < 15) {   // issue next-iteration loads; latency hides under MFMA
            const int kn = (it + 1) * 128;
            ra0 = *(const uint4*)(pa_base + kn + 0);
            ra1 = *(const uint4*)(pa_base + kn + 8);
            ra2 = *(const uint4*)(pa_base + kn + 16);
            ra3 = *(const uint4*)(pa_base + kn + 24);
            rb0 = *(const uint4*)(pb_base + kn + 0);
            rb1 = *(const uint4*)(pb_base + kn + 8);
        }
#pragma unroll
        for (int sub = 0; sub < 4; ++sub) {
            const int kb = sub * 32 + fkb;
            const short8 af = *(const short8*)&sA[w * 16 + fr][kb];
            const short8 b0 = *(const short8*)&sB[ 0 + fr][kb];
            const short8 b1 = *(const short8*)&sB[16 + fr][kb];
            acc[0] = __builtin_amdgcn_mfma_f32_16x16x32_bf16(af, b0, acc[0], 0, 0, 0);
            acc[1] = __builtin_amdgcn_mfma_f32_16x16x32_bf16(af, b1, acc[1], 0, 0, 0);
        }
        __syncthreads();
    }
#pragma unroll
    for (int j = 0; j < 2; ++j) {
        const int col = n0 + j * 16 + fr;
        const float bb = bo2[col];
#pragma unroll
        for (int r = 0; r < 4; ++r) {
            const int row = m0 + w * 16 + (L >> 4) * 4 + r;
            Out[(size_t)row * 256 + col] = acc[j][r] + bb;
        }
    }
}

// ================= fallback: round-3 proven fused kernel =================
#define NT    16
#define NTHR  512
#define NBLK  256
#define TSTR  (C_ + 4)
#define QKSTR (C_ + 8)
#define QSTR  (D_ + 4)
#define WKROW 268

__global__ __launch_bounds__(NTHR)
void t2s_attn_fused(const float* __restrict__ S, const float* __restrict__ T,
                    const float* __restrict__ Wq, const float* __restrict__ bq,
                    const float* __restrict__ Wkv, const float* __restrict__ bkv,
                    const float* __restrict__ Wo, const float* __restrict__ bo,
                    float* __restrict__ Out)
{
    __shared__ float            sQ[NT][H_][QSTR];
    __shared__ float            sWk[16 * WKROW];
    __shared__ float            sT[2][L_][TSTR];
    __shared__ __hip_bfloat16   sQKT[NT][H_][QKSTR];
    __shared__ float            sSc[H_][L_ + 8];
    const int tid = threadIdx.x;
    const int g0  = blockIdx.x * NT;
    float4 tp0, tp1, tp2;
    {
        const float* tb = T + (size_t)g0 * (L_ * C_);
        tp0 = *(const float4*)(tb + 0 * 2048 + tid * 4);
        tp1 = *(const float4*)(tb + 1 * 2048 + tid * 4);
        tp2 = *(const float4*)(tb + 2 * 2048 + tid * 4);
    }
    {
        const int col = tid & 255;
        const int t0  = (tid >> 8) * 8;
        float acc[8];
        const float bqv = bq[col];
#pragma unroll
        for (int j = 0; j < 8; ++j) acc[j] = bqv;
        const float* sp = S + (size_t)(g0 + t0) * C_;
        for (int c = 0; c < C_; ++c) {
            const float w = Wq[c * C_ + col];
#pragma unroll
            for (int j = 0; j < 8; ++j)
                acc[j] = fmaf(sp[j * C_ + c], w, acc[j]);
        }
#pragma unroll
        for (int j = 0; j < 8; ++j)
            sQ[t0 + j][col >> 5][col & 31] = acc[j];
    }
    {
        const int e = tid * 4;
        *(float4*)&sT[0][(e >> 8) +  0][e & 255] = tp0;
        *(float4*)&sT[0][(e >> 8) +  8][e & 255] = tp1;
        *(float4*)&sT[0][(e >> 8) + 16][e & 255] = tp2;
    }
    __syncthreads();
    {
        const int cq = tid & 3;
        const int h  = (tid >> 2) & 7;
        const int t  = tid >> 5;
        for (int ct = 0; ct < 16; ++ct) {
            {
                const int hd  = tid & 255, ci2 = tid >> 8;
                const float* wsrc = Wkv + (size_t)(ct * 16) * 512;
#pragma unroll
                for (int j = 0; j < 8; ++j) {
                    const int ci = ci2 + j * 2;
                    sWk[ci * WKROW + (hd >> 5) * 33 + (hd & 31)] = wsrc[(size_t)ci * 512 + hd];
                }
            }
            __syncthreads();
            float a0 = 0.f, a1 = 0.f, a2 = 0.f, a3 = 0.f;
            const float* qrow = &sQ[t][h][0];
            const float* wb   = &sWk[(cq * 4) * WKROW + h * 33];
#pragma unroll
            for (int d = 0; d < D_; ++d) {
                const float qv = qrow[d];
                a0 = fmaf(qv, wb[0 * WKROW + d], a0);
                a1 = fmaf(qv, wb[1 * WKROW + d], a1);
                a2 = fmaf(qv, wb[2 * WKROW + d], a2);
                a3 = fmaf(qv, wb[3 * WKROW + d], a3);
            }
            const int c0 = ct * 16 + cq * 4;
            sQKT[t][h][c0 + 0] = __float2bfloat16(a0);
            sQKT[t][h][c0 + 1] = __float2bfloat16(a1);
            sQKT[t][h][c0 + 2] = __float2bfloat16(a2);
            sQKT[t][h][c0 + 3] = __float2bfloat16(a3);
            __syncthreads();
        }
    }
    const int lane = tid & 63, wav = tid >> 6;
    for (int t = 0; t < NT; ++t) {
        const int cur = t & 1;
        const bool pf = (t + 1 < NT);
        if (pf) {
            const float* tb = T + (size_t)(g0 + t + 1) * (L_ * C_);
            tp0 = *(const float4*)(tb + 0 * 2048 + tid * 4);
            tp1 = *(const float4*)(tb + 1 * 2048 + tid * 4);
            tp2 = *(const float4*)(tb + 2 * 2048 + tid * 4);
        }
        if (tid < 192) {
            const int h = tid / 24, l = tid - h * 24;
            const float* trow = &sT[cur][l][0];
            const unsigned short* qkr = (const unsigned short*)&sQKT[t][h][0];
            float a0 = 0.f, a1 = 0.f, a2 = 0.f, a3 = 0.f;
            for (int c = 0; c < C_; c += 4) {
                const float4 tv = *(const float4*)(trow + c);
                const uint2  qu = *(const uint2*)(qkr + c);
                a0 = fmaf(tv.x, __uint_as_float(qu.x << 16),          a0);
                a1 = fmaf(tv.y, __uint_as_float(qu.x & 0xffff0000u), a1);
                a2 = fmaf(tv.z, __uint_as_float(qu.y << 16),          a2);
                a3 = fmaf(tv.w, __uint_as_float(qu.y & 0xffff0000u), a3);
            }
            sSc[h][l] = (a0 + a1 + a2 + a3) * 0.17677669529663687f;
        }
        __syncthreads();
        if (tid < 8) {
            float mx = -1e30f;
#pragma unroll
            for (int l = 0; l < L_; ++l) mx = fmaxf(mx, sSc[tid][l]);
            float e[L_]; float sum = 0.f;
#pragma unroll
            for (int l = 0; l < L_; ++l) { e[l] = __expf(sSc[tid][l] - mx); sum += e[l]; }
            const float inv = 1.0f / sum;
#pragma unroll
            for (int l = 0; l < L_; ++l) sSc[tid][l] = e[l] * inv;
        }
        __syncthreads();
        {
            const int h = wav, c0 = lane * 4;
            float ax = 0.f, ay = 0.f, az = 0.f, aw = 0.f;
            const float* at = &sSc[h][0];
#pragma unroll
            for (int l = 0; l < L_; ++l) {
                const float  a  = at[l];
                const float4 tv = *(const float4*)&sT[cur][l][c0];
                ax = fmaf(a, tv.x, ax); ay = fmaf(a, tv.y, ay);
                az = fmaf(a, tv.z, az); aw = fmaf(a, tv.w, aw);
            }
            sQKT[t][h][c0 + 0] = __float2bfloat16(ax);
            sQKT[t][h][c0 + 1] = __float2bfloat16(ay);
            sQKT[t][h][c0 + 2] = __float2bfloat16(az);
            sQKT[t][h][c0 + 3] = __float2bfloat16(aw);
        }
        if (pf) {
            const int e = tid * 4;
            *(float4*)&sT[cur ^ 1][(e >> 8) +  0][e & 255] = tp0;
            *(float4*)&sT[cur ^ 1][(e >> 8) +  8][e & 255] = tp1;
            *(float4*)&sT[cur ^ 1][(e >> 8) + 16][e & 255] = tp2;
        }
        __syncthreads();
    }
    {
        const int hd = tid & 255;
        const int h  = hd >> 5;
        const int t0 = (tid >> 8) * 8;
        float acc[8];
        const float bv = bkv[C_ + hd];
#pragma unroll
        for (int j = 0; j < 8; ++j) acc[j] = bv;
        const float* wv = Wkv + C_ + hd;
        for (int c = 0; c < C_; c += 2) {
            const float w0 = wv[(size_t)c * 512];
            const float w1 = wv[(size_t)(c + 1) * 512];
#pragma unroll
            for (int j = 0; j < 8; ++j) {
                const unsigned int u = *(const unsigned int*)&sQKT[t0 + j][h][c];
                acc[j] = fmaf(__uint_as_float(u << 16),          w0, acc[j]);
                acc[j] = fmaf(__uint_as_float(u & 0xffff0000u), w1, acc[j]);
            }
        }
#pragma unroll
        for (int j = 0; j < 8; ++j)
            sQ[t0 + j][h][hd & 31] = acc[j];
    }
    __syncthreads();
    {
        const int col = tid & 255;
        const int t0  = (tid >> 8) * 8;
        float acc[8];
        const float bov = bo[col];
#pragma unroll
        for (int j = 0; j < 8; ++j) acc[j] = bov;
        for (int hd = 0; hd < C_; ++hd) {
            const float w  = Wo[hd * C_ + col];
            const int  hh = hd >> 5, dd = hd & 31;
#pragma unroll
            for (int j = 0; j < 8; ++j)
                acc[j] = fmaf(sQ[t0 + j][hh][dd], w, acc[j]);
        }
#pragma unroll
        for (int j = 0; j < 8; ++j)
            Out[(size_t)(g0 + t0 + j) * C_ + col] = acc[j];
    }
}

extern "C" void kernel_launch(void* const* d_in, const int* in_sizes, int n_in,
                              void* d_out, int out_size, void* d_ws, size_t ws_size,
                              hipStream_t stream) {
    const float* S   = (const float*)d_in[0];
    const float* T   = (const float*)d_in[1];
    const float* Wq  = (const float*)d_in[2];
    const float* bq  = (const float*)d_in[3];
    const float* Wkv = (const float*)d_in[4];
    const float* bkv = (const float*)d_in[5];
    const float* Wo  = (const float*)d_in[6];
    const float* bo  = (const float*)d_in[7];
    float* Out = (float*)d_out;
    if (ws_size >= WS_NEED) {
        char* ws = (char*)d_ws;
        hipLaunchKernelGGL(k_pre,  dim3(130),  dim3(256), 0, stream, Wq, bq, Wkv, bkv, Wo, bo, ws);
        hipLaunchKernelGGL(k_qk,   dim3(2048), dim3(256), 0, stream, S, ws);
        hipLaunchKernelGGL(k_attn, dim3(4096), dim3(256), 0, stream, T, ws);
        hipLaunchKernelGGL(k_out,  dim3(512),  dim3(256), 0, stream, ws, Out);
    } else {
        hipLaunchKernelGGL(t2s_attn_fused, dim3(NBLK), dim3(NTHR), 0, stream,
                           S, T, Wq, bq, Wkv, bkv, Wo, bo, Out);
    }
}